// Round 2
// baseline (19733.160 us; speedup 1.0000x reference)
//
#include <hip/hip_runtime.h>
#include <math.h>

// BiLSTM-CRF fp32, round 2: input GEMM fused into the recurrence (K=512).
// ws layout (floats): x[16384*256] | hs_f[32*512*256] | hs_b[32*512*256] |
//                     c_f[512*256] | c_b[512*256] | feats[16384*11]   (~52 MiB)
// Output: d_out[0:32]=score(f32), d_out[32:32+16384]=path (float-encoded ints).

namespace {

constexpr int E_ = 256;    // embed dim
constexpr int H_ = 256;    // hidden per dir
constexpr int T_ = 11;     // tags

// ---------------- K1: embedding gather ----------------
__global__ __launch_bounds__(256) void k_gather(const int* __restrict__ sent,
                                                const float* __restrict__ embed,
                                                float* __restrict__ x) {
  int i = blockIdx.x * 256 + threadIdx.x;   // float4 id over 16384*64
  int row = i >> 6;
  int e = (i & 63) << 2;
  int tok = sent[row];
  *(float4*)(x + (size_t)row * E_ + e) =
      *(const float4*)(embed + (size_t)tok * E_ + e);
}

// ---------------- K2: one fused LSTM step, K=512 ([x_t | h_prev]) ----------------
// Grid: (cb 0..15, rb 0..15, d 0..1) = 512 blocks, 256 threads.
// Block tile: 32 s-rows x 64 gate-cols (col = q*16 + jj, q in {i,f,g,o}, j = cb*16+jj).
// Wave owns 8 rows x 64 cols; lane owns 1 col. A read = LDS broadcast, B read = b32.
__global__ __launch_bounds__(256, 2) void k_step(
    const float* __restrict__ x,
    const float* __restrict__ w_ih_f, const float* __restrict__ w_hh_f,
    const float* __restrict__ b_ih_f, const float* __restrict__ b_hh_f,
    const float* __restrict__ w_ih_b, const float* __restrict__ w_hh_b,
    const float* __restrict__ b_ih_b, const float* __restrict__ b_hh_b,
    const float* __restrict__ h0, const float* __restrict__ c0,
    float* __restrict__ hs_f, float* __restrict__ hs_b,
    float* __restrict__ c_f, float* __restrict__ c_b, int t) {
  __shared__ __align__(16) float As[2][32][32];   // [buf][s-row][k]   8 KiB
  __shared__ __align__(16) float Bs[2][32][64];   // [buf][k][col]    16 KiB
  __shared__ __align__(16) float Cs[32][64];      // gates             8 KiB
  const int tid = threadIdx.x;
  const int cb = blockIdx.x, rb = blockIdx.y, d = blockIdx.z;
  const int s0 = rb * 32, j0 = cb * 16;
  const float* wih = d ? w_ih_b : w_ih_f;
  const float* whh = d ? w_hh_b : w_hh_f;
  const int tt = d ? 31 - t : t;                  // time slice of x
  const float* xs = x + (size_t)tt * 512 * E_;
  const float* hprev = (t == 0) ? h0 + (size_t)d * 512 * H_
                      : (d ? hs_b + (size_t)(32 - t) * 512 * H_
                           : hs_f + (size_t)(t - 1) * 512 * H_);
  float* hout = d ? hs_b + (size_t)(31 - t) * 512 * H_
                  : hs_f + (size_t)t * 512 * H_;
  float* cbuf = d ? c_b : c_f;
  const float* cprev = (t == 0) ? c0 + (size_t)d * 512 * H_ : cbuf;

  const int wv = tid >> 6, lane = tid & 63;
  const int ar = tid >> 3, akq = tid & 7;         // As stage: row, k-quad
  const int bc = tid >> 2, bkq2 = tid & 3;        // Bs stage: col, quads bkq2 & bkq2+4
  const float* browi = wih + (size_t)((bc >> 4) * 256 + j0 + (bc & 15)) * E_;
  const float* browh = whh + (size_t)((bc >> 4) * 256 + j0 + (bc & 15)) * H_;
  const float* arow_x = xs + (size_t)(s0 + ar) * E_;
  const float* arow_h = hprev + (size_t)(s0 + ar) * H_;

  float acc[8];
#pragma unroll
  for (int r = 0; r < 8; ++r) acc[r] = 0.f;

  // prologue: stage chunk 0 (x part, k0 = 0)
  {
    float4 av = *(const float4*)(arow_x + akq * 4);
    float4 b0 = *(const float4*)(browi + bkq2 * 4);
    float4 b1 = *(const float4*)(browi + 16 + bkq2 * 4);
    *(float4*)&As[0][ar][akq * 4] = av;
    Bs[0][bkq2*4+0][bc]=b0.x; Bs[0][bkq2*4+1][bc]=b0.y; Bs[0][bkq2*4+2][bc]=b0.z; Bs[0][bkq2*4+3][bc]=b0.w;
    Bs[0][bkq2*4+16][bc]=b1.x; Bs[0][bkq2*4+17][bc]=b1.y; Bs[0][bkq2*4+18][bc]=b1.z; Bs[0][bkq2*4+19][bc]=b1.w;
  }
  __syncthreads();

#pragma unroll 2
  for (int ci = 0; ci < 16; ++ci) {
    const int buf = ci & 1;
    const bool st = (ci < 15);
    float4 av, b0, b1;
    if (st) {   // T14: issue next-chunk global loads BEFORE the FMA block
      int k0n = (ci + 1) * 32;
      if (k0n < 256) {
        av = *(const float4*)(arow_x + k0n + akq * 4);
        b0 = *(const float4*)(browi + k0n + bkq2 * 4);
        b1 = *(const float4*)(browi + k0n + 16 + bkq2 * 4);
      } else {
        int kh = k0n - 256;
        av = *(const float4*)(arow_h + kh + akq * 4);
        b0 = *(const float4*)(browh + kh + bkq2 * 4);
        b1 = *(const float4*)(browh + kh + 16 + bkq2 * 4);
      }
    }
#pragma unroll
    for (int kq = 0; kq < 8; ++kq) {
      float a_[8][4];
#pragma unroll
      for (int r = 0; r < 8; ++r)
        *(float4*)a_[r] = *(const float4*)&As[buf][wv * 8 + r][kq * 4];  // broadcast
#pragma unroll
      for (int j = 0; j < 4; ++j) {
        float b = Bs[buf][kq * 4 + j][lane];
#pragma unroll
        for (int r = 0; r < 8; ++r) acc[r] = fmaf(a_[r][j], b, acc[r]);
      }
    }
    if (st) {   // reg -> LDS (other buffer), after compute
      int nb = buf ^ 1;
      *(float4*)&As[nb][ar][akq * 4] = av;
      Bs[nb][bkq2*4+0][bc]=b0.x; Bs[nb][bkq2*4+1][bc]=b0.y; Bs[nb][bkq2*4+2][bc]=b0.z; Bs[nb][bkq2*4+3][bc]=b0.w;
      Bs[nb][bkq2*4+16][bc]=b1.x; Bs[nb][bkq2*4+17][bc]=b1.y; Bs[nb][bkq2*4+18][bc]=b1.z; Bs[nb][bkq2*4+19][bc]=b1.w;
    }
    __syncthreads();
  }

#pragma unroll
  for (int r = 0; r < 8; ++r) Cs[wv * 8 + r][lane] = acc[r];
  __syncthreads();

  // pointwise epilogue: 512 cells (32 s x 16 j), 2 per thread
  const float* bi = d ? b_ih_b : b_ih_f;
  const float* bh = d ? b_hh_b : b_hh_f;
#pragma unroll
  for (int u = 0; u < 2; ++u) {
    int idx = tid + 256 * u;
    int sl = idx >> 4, jj = idx & 15;
    int s = s0 + sl, j = j0 + jj;
    float gi = Cs[sl][jj]      + bi[j]       + bh[j];
    float gf = Cs[sl][16 + jj] + bi[256 + j] + bh[256 + j];
    float gg = Cs[sl][32 + jj] + bi[512 + j] + bh[512 + j];
    float go = Cs[sl][48 + jj] + bi[768 + j] + bh[768 + j];
    float si = 1.f / (1.f + expf(-gi));
    float sf = 1.f / (1.f + expf(-gf));
    float tg = tanhf(gg);
    float so = 1.f / (1.f + expf(-go));
    float cp = cprev[(size_t)s * H_ + j];
    float cn = sf * cp + si * tg;
    float hn = so * tanhf(cn);
    cbuf[(size_t)s * H_ + j] = cn;
    hout[(size_t)s * H_ + j] = hn;
  }
}

// ---------------- K3: feats = [hs_f|hs_b] @ w_out.T + b_out ----------------
__global__ __launch_bounds__(256) void k_out_gemm(
    const float* __restrict__ hs_f, const float* __restrict__ hs_b,
    const float* __restrict__ w_out, const float* __restrict__ b_out,
    float* __restrict__ feats) {
  __shared__ __align__(16) float wl[T_ * 512];
  for (int i = threadIdx.x; i < T_ * 512; i += 256) wl[i] = w_out[i];
  __syncthreads();
  int wave = threadIdx.x >> 6, lane = threadIdx.x & 63;
  size_t row = (size_t)blockIdx.x * 4 + wave;   // 0..16383
  float4 hf = *(const float4*)(hs_f + row * H_ + lane * 4);
  float4 hb = *(const float4*)(hs_b + row * H_ + lane * 4);
#pragma unroll
  for (int tag = 0; tag < T_; ++tag) {
    float4 wf = *(const float4*)&wl[tag * 512 + lane * 4];
    float4 wb = *(const float4*)&wl[tag * 512 + 256 + lane * 4];
    float p = hf.x * wf.x + hf.y * wf.y + hf.z * wf.z + hf.w * wf.w +
              hb.x * wb.x + hb.y * wb.y + hb.z * wb.z + hb.w * wb.w;
#pragma unroll
    for (int off = 32; off; off >>= 1) p += __shfl_xor(p, off, 64);
    if (lane == 0) feats[row * T_ + tag] = p + b_out[tag];
  }
}

// ---------------- K4: Viterbi fwd + backtrack, one wave per batch elem ----------------
__global__ __launch_bounds__(64) void k_viterbi(const float* __restrict__ feats,
                                                const float* __restrict__ trans,
                                                float* __restrict__ out) {
  __shared__ float fl[512 * T_];
  __shared__ unsigned char psi[511 * T_];
  const int b = blockIdx.x, tid = threadIdx.x;
  const float* fb = feats + (size_t)b * 512 * T_;
  for (int i = tid; i < 512 * T_; i += 64) fl[i] = fb[i];
  const int to = (tid < T_) ? tid : 0;
  float tr[T_];
#pragma unroll
  for (int f = 0; f < T_; ++f) tr[f] = trans[to * T_ + f];
  float delta = (tid == 9) ? 0.f : -10000.f;   // START=9
  __syncthreads();

  for (int s = 1; s < 512; ++s) {
    float m = -3.4e38f;
    int am = 0;
#pragma unroll
    for (int f = 0; f < T_; ++f) {
      float v = tr[f] + __shfl(delta, f, 64);
      if (v > m) { m = v; am = f; }          // strict >: first-max (jnp.argmax)
    }
    float nd = m + fl[s * T_ + to];
    if (tid < T_) psi[(s - 1) * T_ + tid] = (unsigned char)am;
    delta = nd;
  }
  float m = -3.4e38f;
  int last = 0;
#pragma unroll
  for (int j = 0; j < T_; ++j) {
    float v = __shfl(delta, j, 64);
    if (v > m) { m = v; last = j; }
  }
  __syncthreads();
  if (tid == 0) {
    out[b] = m;
    float* path = out + 32 + (size_t)b * 512;
    path[511] = (float)last;
    int nxt = last;
    for (int k = 510; k >= 0; --k) {
      nxt = psi[k * T_ + nxt];
      path[k] = (float)nxt;
    }
  }
}

}  // namespace

extern "C" void kernel_launch(void* const* d_in, const int* in_sizes, int n_in,
                              void* d_out, int out_size, void* d_ws, size_t ws_size,
                              hipStream_t stream) {
  const int* sent     = (const int*)d_in[0];
  const float* embed  = (const float*)d_in[1];
  const float* w_ih_f = (const float*)d_in[2];
  const float* w_hh_f = (const float*)d_in[3];
  const float* b_ih_f = (const float*)d_in[4];
  const float* b_hh_f = (const float*)d_in[5];
  const float* w_ih_b = (const float*)d_in[6];
  const float* w_hh_b = (const float*)d_in[7];
  const float* b_ih_b = (const float*)d_in[8];
  const float* b_hh_b = (const float*)d_in[9];
  const float* h0     = (const float*)d_in[10];
  const float* c0     = (const float*)d_in[11];
  const float* w_out  = (const float*)d_in[12];
  const float* b_out  = (const float*)d_in[13];
  const float* trans  = (const float*)d_in[14];

  float* ws    = (float*)d_ws;
  float* x     = ws;                 // 16384*256 = 4,194,304
  float* hs_f  = x + 4194304;        // 32*512*256 = 4,194,304
  float* hs_b  = hs_f + 4194304;     // 4,194,304
  float* c_f   = hs_b + 4194304;     // 131,072
  float* c_b   = c_f + 131072;       // 131,072
  float* feats = c_b + 131072;       // 180,224
  // total ~12.9M floats = ~52 MiB of ws

  k_gather<<<4096, 256, 0, stream>>>(sent, embed, x);
  for (int t = 0; t < 32; ++t)
    k_step<<<dim3(16, 16, 2), 256, 0, stream>>>(
        x, w_ih_f, w_hh_f, b_ih_f, b_hh_f, w_ih_b, w_hh_b, b_ih_b, b_hh_b,
        h0, c0, hs_f, hs_b, c_f, c_b, t);
  k_out_gemm<<<4096, 256, 0, stream>>>(hs_f, hs_b, w_out, b_out, feats);
  k_viterbi<<<32, 64, 0, stream>>>(feats, trans, (float*)d_out);
}

// Round 3
// 15358.540 us; speedup vs baseline: 1.2848x; 1.2848x over previous
//
#include <hip/hip_runtime.h>
#include <math.h>

// BiLSTM-CRF fp32, round 3: round-2 structure with the scratch-spill fixed
// (no float-array punning; float4 locals only) + XCD-ownership block swizzle.
// ws layout (floats): x[16384*256] | hs_f[32*512*256] | hs_b[32*512*256] |
//                     c_f[512*256] | c_b[512*256] | feats[16384*11]   (~52 MiB)
// Output: d_out[0:32]=score(f32), d_out[32:32+16384]=path (float-encoded ints).

namespace {

constexpr int E_ = 256;    // embed dim
constexpr int H_ = 256;    // hidden per dir
constexpr int T_ = 11;     // tags

// ---------------- K1: embedding gather ----------------
__global__ __launch_bounds__(256) void k_gather(const int* __restrict__ sent,
                                                const float* __restrict__ embed,
                                                float* __restrict__ x) {
  int i = blockIdx.x * 256 + threadIdx.x;   // float4 id over 16384*64
  int row = i >> 6;
  int e = (i & 63) << 2;
  int tok = sent[row];
  *(float4*)(x + (size_t)row * E_ + e) =
      *(const float4*)(embed + (size_t)tok * E_ + e);
}

// ---------------- K2: one fused LSTM step, K=512 ([x_t | h_prev]) ----------------
// 512 blocks, 256 threads. Block tile: 32 s-rows x 64 gate-cols
// (col = q*16 + jj, q in {i,f,g,o}, j = cb*16+jj). Wave owns 8 rows x 64 cols;
// lane owns 1 col. A read = LDS b128 broadcast, B read = conflict-free b32.
// Block swizzle: XCD x owns colgroups 4x..4x+3 (round-robin dispatch assumption);
// weights per XCD = 512 KB -> L2-resident across all 32 steps.
__global__ __launch_bounds__(256, 2) void k_step(
    const float* __restrict__ x,
    const float* __restrict__ w_ih_f, const float* __restrict__ w_hh_f,
    const float* __restrict__ b_ih_f, const float* __restrict__ b_hh_f,
    const float* __restrict__ w_ih_b, const float* __restrict__ w_hh_b,
    const float* __restrict__ b_ih_b, const float* __restrict__ b_hh_b,
    const float* __restrict__ h0, const float* __restrict__ c0,
    float* __restrict__ hs_f, float* __restrict__ hs_b,
    float* __restrict__ c_f, float* __restrict__ c_b, int t) {
  __shared__ __align__(16) float As[2][32][32];   // [buf][s-row][k]   8 KiB
  __shared__ __align__(16) float Bs[2][32][64];   // [buf][k][col]    16 KiB
  __shared__ __align__(16) float Cs[32][64];      // gates             8 KiB
  const int tid = threadIdx.x;
  // XCD-ownership swizzle (perf heuristic only)
  const int gid = blockIdx.x;            // 0..511
  const int xcd = gid & 7, slot = gid >> 3;
  const int cg = xcd * 4 + (slot >> 4);  // colgroup 0..31 = (d, cb)
  const int rb = slot & 15;
  const int d = cg >> 4, cb = cg & 15;

  const int s0 = rb * 32, j0 = cb * 16;
  const float* wih = d ? w_ih_b : w_ih_f;
  const float* whh = d ? w_hh_b : w_hh_f;
  const int tt = d ? 31 - t : t;                  // time slice of x
  const float* xs = x + (size_t)tt * 512 * E_;
  const float* hprev = (t == 0) ? h0 + (size_t)d * 512 * H_
                      : (d ? hs_b + (size_t)(32 - t) * 512 * H_
                           : hs_f + (size_t)(t - 1) * 512 * H_);
  float* hout = d ? hs_b + (size_t)(31 - t) * 512 * H_
                  : hs_f + (size_t)t * 512 * H_;
  float* cbuf = d ? c_b : c_f;
  const float* cprev = (t == 0) ? c0 + (size_t)d * 512 * H_ : cbuf;

  const int wv = tid >> 6, lane = tid & 63;
  const int ar = tid >> 3, akq = tid & 7;         // As stage: row, k-quad
  const int bc = tid >> 2, bkq2 = tid & 3;        // Bs stage: col, quads bkq2 & bkq2+4
  const float* browi = wih + (size_t)((bc >> 4) * 256 + j0 + (bc & 15)) * E_;
  const float* browh = whh + (size_t)((bc >> 4) * 256 + j0 + (bc & 15)) * H_;
  const float* arow_x = xs + (size_t)(s0 + ar) * E_;
  const float* arow_h = hprev + (size_t)(s0 + ar) * H_;

  float acc[8];
#pragma unroll
  for (int r = 0; r < 8; ++r) acc[r] = 0.f;

  // prologue: stage chunk 0 (x part, k0 = 0)
  {
    float4 av = *(const float4*)(arow_x + akq * 4);
    float4 b0 = *(const float4*)(browi + bkq2 * 4);
    float4 b1 = *(const float4*)(browi + 16 + bkq2 * 4);
    *(float4*)&As[0][ar][akq * 4] = av;
    Bs[0][bkq2*4+0][bc]=b0.x; Bs[0][bkq2*4+1][bc]=b0.y; Bs[0][bkq2*4+2][bc]=b0.z; Bs[0][bkq2*4+3][bc]=b0.w;
    Bs[0][bkq2*4+16][bc]=b1.x; Bs[0][bkq2*4+17][bc]=b1.y; Bs[0][bkq2*4+18][bc]=b1.z; Bs[0][bkq2*4+19][bc]=b1.w;
  }
  __syncthreads();

#pragma unroll 2
  for (int ci = 0; ci < 16; ++ci) {
    const int buf = ci & 1;
    const bool st = (ci < 15);
    float4 av, b0, b1;
    if (st) {   // T14: issue next-chunk global loads BEFORE the FMA block
      int k0n = (ci + 1) * 32;
      if (k0n < 256) {
        av = *(const float4*)(arow_x + k0n + akq * 4);
        b0 = *(const float4*)(browi + k0n + bkq2 * 4);
        b1 = *(const float4*)(browi + k0n + 16 + bkq2 * 4);
      } else {
        int kh = k0n - 256;
        av = *(const float4*)(arow_h + kh + akq * 4);
        b0 = *(const float4*)(browh + kh + bkq2 * 4);
        b1 = *(const float4*)(browh + kh + 16 + bkq2 * 4);
      }
    }
#pragma unroll
    for (int kq = 0; kq < 8; ++kq) {
      float bb0 = Bs[buf][kq * 4 + 0][lane];
      float bb1 = Bs[buf][kq * 4 + 1][lane];
      float bb2 = Bs[buf][kq * 4 + 2][lane];
      float bb3 = Bs[buf][kq * 4 + 3][lane];
#pragma unroll
      for (int r = 0; r < 8; ++r) {
        float4 a = *(const float4*)&As[buf][wv * 8 + r][kq * 4];  // broadcast
        acc[r] = fmaf(a.x, bb0, acc[r]);
        acc[r] = fmaf(a.y, bb1, acc[r]);
        acc[r] = fmaf(a.z, bb2, acc[r]);
        acc[r] = fmaf(a.w, bb3, acc[r]);
      }
    }
    if (st) {   // reg -> LDS (other buffer), after compute
      int nb = buf ^ 1;
      *(float4*)&As[nb][ar][akq * 4] = av;
      Bs[nb][bkq2*4+0][bc]=b0.x; Bs[nb][bkq2*4+1][bc]=b0.y; Bs[nb][bkq2*4+2][bc]=b0.z; Bs[nb][bkq2*4+3][bc]=b0.w;
      Bs[nb][bkq2*4+16][bc]=b1.x; Bs[nb][bkq2*4+17][bc]=b1.y; Bs[nb][bkq2*4+18][bc]=b1.z; Bs[nb][bkq2*4+19][bc]=b1.w;
    }
    __syncthreads();
  }

#pragma unroll
  for (int r = 0; r < 8; ++r) Cs[wv * 8 + r][lane] = acc[r];
  __syncthreads();

  // pointwise epilogue: 512 cells (32 s x 16 j), 2 per thread
  const float* bi = d ? b_ih_b : b_ih_f;
  const float* bh = d ? b_hh_b : b_hh_f;
#pragma unroll
  for (int u = 0; u < 2; ++u) {
    int idx = tid + 256 * u;
    int sl = idx >> 4, jj = idx & 15;
    int s = s0 + sl, j = j0 + jj;
    float gi = Cs[sl][jj]      + bi[j]       + bh[j];
    float gf = Cs[sl][16 + jj] + bi[256 + j] + bh[256 + j];
    float gg = Cs[sl][32 + jj] + bi[512 + j] + bh[512 + j];
    float go = Cs[sl][48 + jj] + bi[768 + j] + bh[768 + j];
    float si = 1.f / (1.f + expf(-gi));
    float sf = 1.f / (1.f + expf(-gf));
    float tg = tanhf(gg);
    float so = 1.f / (1.f + expf(-go));
    float cp = cprev[(size_t)s * H_ + j];
    float cn = sf * cp + si * tg;
    float hn = so * tanhf(cn);
    cbuf[(size_t)s * H_ + j] = cn;
    hout[(size_t)s * H_ + j] = hn;
  }
}

// ---------------- K3: feats = [hs_f|hs_b] @ w_out.T + b_out ----------------
__global__ __launch_bounds__(256) void k_out_gemm(
    const float* __restrict__ hs_f, const float* __restrict__ hs_b,
    const float* __restrict__ w_out, const float* __restrict__ b_out,
    float* __restrict__ feats) {
  __shared__ __align__(16) float wl[T_ * 512];
  for (int i = threadIdx.x; i < T_ * 512; i += 256) wl[i] = w_out[i];
  __syncthreads();
  int wave = threadIdx.x >> 6, lane = threadIdx.x & 63;
  size_t row = (size_t)blockIdx.x * 4 + wave;   // 0..16383
  float4 hf = *(const float4*)(hs_f + row * H_ + lane * 4);
  float4 hb = *(const float4*)(hs_b + row * H_ + lane * 4);
#pragma unroll
  for (int tag = 0; tag < T_; ++tag) {
    float4 wf = *(const float4*)&wl[tag * 512 + lane * 4];
    float4 wb = *(const float4*)&wl[tag * 512 + 256 + lane * 4];
    float p = hf.x * wf.x + hf.y * wf.y + hf.z * wf.z + hf.w * wf.w +
              hb.x * wb.x + hb.y * wb.y + hb.z * wb.z + hb.w * wb.w;
#pragma unroll
    for (int off = 32; off; off >>= 1) p += __shfl_xor(p, off, 64);
    if (lane == 0) feats[row * T_ + tag] = p + b_out[tag];
  }
}

// ---------------- K4: Viterbi fwd + backtrack, one wave per batch elem ----------------
__global__ __launch_bounds__(64) void k_viterbi(const float* __restrict__ feats,
                                                const float* __restrict__ trans,
                                                float* __restrict__ out) {
  __shared__ float fl[512 * T_];
  __shared__ unsigned char psi[511 * T_];
  const int b = blockIdx.x, tid = threadIdx.x;
  const float* fb = feats + (size_t)b * 512 * T_;
  for (int i = tid; i < 512 * T_; i += 64) fl[i] = fb[i];
  const int to = (tid < T_) ? tid : 0;
  float tr[T_];
#pragma unroll
  for (int f = 0; f < T_; ++f) tr[f] = trans[to * T_ + f];
  float delta = (tid == 9) ? 0.f : -10000.f;   // START=9
  __syncthreads();

  for (int s = 1; s < 512; ++s) {
    float m = -3.4e38f;
    int am = 0;
#pragma unroll
    for (int f = 0; f < T_; ++f) {
      float v = tr[f] + __shfl(delta, f, 64);
      if (v > m) { m = v; am = f; }          // strict >: first-max (jnp.argmax)
    }
    float nd = m + fl[s * T_ + to];
    if (tid < T_) psi[(s - 1) * T_ + tid] = (unsigned char)am;
    delta = nd;
  }
  float m = -3.4e38f;
  int last = 0;
#pragma unroll
  for (int j = 0; j < T_; ++j) {
    float v = __shfl(delta, j, 64);
    if (v > m) { m = v; last = j; }
  }
  __syncthreads();
  if (tid == 0) {
    out[b] = m;
    float* path = out + 32 + (size_t)b * 512;
    path[511] = (float)last;
    int nxt = last;
    for (int k = 510; k >= 0; --k) {
      nxt = psi[k * T_ + nxt];
      path[k] = (float)nxt;
    }
  }
}

}  // namespace

extern "C" void kernel_launch(void* const* d_in, const int* in_sizes, int n_in,
                              void* d_out, int out_size, void* d_ws, size_t ws_size,
                              hipStream_t stream) {
  const int* sent     = (const int*)d_in[0];
  const float* embed  = (const float*)d_in[1];
  const float* w_ih_f = (const float*)d_in[2];
  const float* w_hh_f = (const float*)d_in[3];
  const float* b_ih_f = (const float*)d_in[4];
  const float* b_hh_f = (const float*)d_in[5];
  const float* w_ih_b = (const float*)d_in[6];
  const float* w_hh_b = (const float*)d_in[7];
  const float* b_ih_b = (const float*)d_in[8];
  const float* b_hh_b = (const float*)d_in[9];
  const float* h0     = (const float*)d_in[10];
  const float* c0     = (const float*)d_in[11];
  const float* w_out  = (const float*)d_in[12];
  const float* b_out  = (const float*)d_in[13];
  const float* trans  = (const float*)d_in[14];

  float* ws    = (float*)d_ws;
  float* x     = ws;                 // 16384*256 = 4,194,304
  float* hs_f  = x + 4194304;        // 32*512*256 = 4,194,304
  float* hs_b  = hs_f + 4194304;     // 4,194,304
  float* c_f   = hs_b + 4194304;     // 131,072
  float* c_b   = c_f + 131072;       // 131,072
  float* feats = c_b + 131072;       // 180,224
  // total ~12.9M floats = ~52 MiB of ws

  k_gather<<<4096, 256, 0, stream>>>(sent, embed, x);
  for (int t = 0; t < 32; ++t)
    k_step<<<512, 256, 0, stream>>>(
        x, w_ih_f, w_hh_f, b_ih_f, b_hh_f, w_ih_b, w_hh_b, b_ih_b, b_hh_b,
        h0, c0, hs_f, hs_b, c_f, c_b, t);
  k_out_gemm<<<4096, 256, 0, stream>>>(hs_f, hs_b, w_out, b_out, feats);
  k_viterbi<<<32, 64, 0, stream>>>(feats, trans, (float*)d_out);
}

// Round 4
// 1757.730 us; speedup vs baseline: 11.2265x; 8.7377x over previous
//
#include <hip/hip_runtime.h>
#include <math.h>

// BiLSTM-CRF fp32, round 4: fused K=512 step with SIMPLE single-buffered
// staging (round-1 protocol) + rd3 inner loop. Differential experiment vs the
// rd2/rd3 double-buffer+prefetch structure that showed 2.2GB/step phantom HBM
// traffic.
// ws layout (floats): x[16384*256] | hs_f[32*512*256] | hs_b[32*512*256] |
//                     c_f[512*256] | c_b[512*256] | feats[16384*11]   (~52 MiB)
// Output: d_out[0:32]=score(f32), d_out[32:32+16384]=path (float-encoded ints).

namespace {

constexpr int E_ = 256;    // embed dim
constexpr int H_ = 256;    // hidden per dir
constexpr int T_ = 11;     // tags

// ---------------- K1: embedding gather ----------------
__global__ __launch_bounds__(256) void k_gather(const int* __restrict__ sent,
                                                const float* __restrict__ embed,
                                                float* __restrict__ x) {
  int i = blockIdx.x * 256 + threadIdx.x;   // float4 id over 16384*64
  int row = i >> 6;
  int e = (i & 63) << 2;
  int tok = sent[row];
  *(float4*)(x + (size_t)row * E_ + e) =
      *(const float4*)(embed + (size_t)tok * E_ + e);
}

// ---------------- K2: one fused LSTM step, K=512 ([x_t | h_prev]) ----------------
// 512 blocks, 256 threads. Block tile: 32 s-rows x 64 gate-cols
// (col = q*16 + jj, q in {i,f,g,o}, j = cb*16+jj). Wave owns 8 rows x 64 cols;
// lane owns 1 col. Per chunk (BK=64): stage -> barrier -> FMA -> barrier.
__global__ __launch_bounds__(256) void k_step(
    const float* __restrict__ x,
    const float* __restrict__ w_ih_f, const float* __restrict__ w_hh_f,
    const float* __restrict__ b_ih_f, const float* __restrict__ b_hh_f,
    const float* __restrict__ w_ih_b, const float* __restrict__ w_hh_b,
    const float* __restrict__ b_ih_b, const float* __restrict__ b_hh_b,
    const float* __restrict__ h0, const float* __restrict__ c0,
    float* __restrict__ hs_f, float* __restrict__ hs_b,
    float* __restrict__ c_f, float* __restrict__ c_b, int t) {
  __shared__ __align__(16) float As[32][64];   // [s][k]    8 KiB
  __shared__ float Bs[64][65];                 // [k][col] 16.25 KiB (padded)
  __shared__ float Cs[32][65];                 // gates     8.125 KiB (padded)
  const int tid = threadIdx.x;
  // XCD-ownership swizzle (perf heuristic only)
  const int gid = blockIdx.x;            // 0..511
  const int xcd = gid & 7, slot = gid >> 3;
  const int cg = xcd * 4 + (slot >> 4);  // colgroup 0..31 = (d, cb)
  const int rb = slot & 15;
  const int d = cg >> 4, cb = cg & 15;

  const int s0 = rb * 32, j0 = cb * 16;
  const float* wih = d ? w_ih_b : w_ih_f;
  const float* whh = d ? w_hh_b : w_hh_f;
  const int tt = d ? 31 - t : t;                  // time slice of x
  const float* xs = x + (size_t)tt * 512 * E_;
  const float* hprev = (t == 0) ? h0 + (size_t)d * 512 * H_
                      : (d ? hs_b + (size_t)(32 - t) * 512 * H_
                           : hs_f + (size_t)(t - 1) * 512 * H_);
  float* hout = d ? hs_b + (size_t)(31 - t) * 512 * H_
                  : hs_f + (size_t)t * 512 * H_;
  float* cbuf = d ? c_b : c_f;
  const float* cprev = (t == 0) ? c0 + (size_t)d * 512 * H_ : cbuf;

  const int wv = tid >> 6, lane = tid & 63;
  const int ar = tid >> 3, akq = tid & 7;         // As stage: row, k-quad
  const int bc = tid >> 2, bkq2 = tid & 3;        // Bs stage: col, k-quad base
  const float* browi = wih + (size_t)((bc >> 4) * 256 + j0 + (bc & 15)) * E_;
  const float* browh = whh + (size_t)((bc >> 4) * 256 + j0 + (bc & 15)) * H_;
  const float* arow_x = xs + (size_t)(s0 + ar) * E_;
  const float* arow_h = hprev + (size_t)(s0 + ar) * H_;

  float acc[8];
#pragma unroll
  for (int r = 0; r < 8; ++r) acc[r] = 0.f;

  for (int ci = 0; ci < 8; ++ci) {
    const int k0 = ci * 64;
    const float* as_ = (k0 < 256) ? (arow_x + k0) : (arow_h + (k0 - 256));
    const float* bs_ = (k0 < 256) ? (browi + k0) : (browh + (k0 - 256));
    // stage A: 2 float4/thread
    float4 a0 = *(const float4*)(as_ + akq * 4);
    float4 a1 = *(const float4*)(as_ + 32 + akq * 4);
    // stage B: 4 float4/thread (one W row per 4 threads)
    float4 w0 = *(const float4*)(bs_ + bkq2 * 4);
    float4 w1 = *(const float4*)(bs_ + 16 + bkq2 * 4);
    float4 w2 = *(const float4*)(bs_ + 32 + bkq2 * 4);
    float4 w3 = *(const float4*)(bs_ + 48 + bkq2 * 4);
    *(float4*)&As[ar][akq * 4] = a0;
    *(float4*)&As[ar][32 + akq * 4] = a1;
    const int kb = bkq2 * 4;
    Bs[kb + 0][bc] = w0.x;  Bs[kb + 1][bc] = w0.y;  Bs[kb + 2][bc] = w0.z;  Bs[kb + 3][bc] = w0.w;
    Bs[kb + 16][bc] = w1.x; Bs[kb + 17][bc] = w1.y; Bs[kb + 18][bc] = w1.z; Bs[kb + 19][bc] = w1.w;
    Bs[kb + 32][bc] = w2.x; Bs[kb + 33][bc] = w2.y; Bs[kb + 34][bc] = w2.z; Bs[kb + 35][bc] = w2.w;
    Bs[kb + 48][bc] = w3.x; Bs[kb + 49][bc] = w3.y; Bs[kb + 50][bc] = w3.z; Bs[kb + 51][bc] = w3.w;
    __syncthreads();
#pragma unroll
    for (int kq = 0; kq < 16; ++kq) {
      float bb0 = Bs[kq * 4 + 0][lane];
      float bb1 = Bs[kq * 4 + 1][lane];
      float bb2 = Bs[kq * 4 + 2][lane];
      float bb3 = Bs[kq * 4 + 3][lane];
#pragma unroll
      for (int r = 0; r < 8; ++r) {
        float4 a = *(const float4*)&As[wv * 8 + r][kq * 4];  // broadcast b128
        acc[r] = fmaf(a.x, bb0, acc[r]);
        acc[r] = fmaf(a.y, bb1, acc[r]);
        acc[r] = fmaf(a.z, bb2, acc[r]);
        acc[r] = fmaf(a.w, bb3, acc[r]);
      }
    }
    __syncthreads();
  }

#pragma unroll
  for (int r = 0; r < 8; ++r) Cs[wv * 8 + r][lane] = acc[r];
  __syncthreads();

  // pointwise epilogue: 512 cells (32 s x 16 j), 2 per thread
  const float* bi = d ? b_ih_b : b_ih_f;
  const float* bh = d ? b_hh_b : b_hh_f;
#pragma unroll
  for (int u = 0; u < 2; ++u) {
    int idx = tid + 256 * u;
    int sl = idx >> 4, jj = idx & 15;
    int s = s0 + sl, j = j0 + jj;
    float gi = Cs[sl][jj]      + bi[j]       + bh[j];
    float gf = Cs[sl][16 + jj] + bi[256 + j] + bh[256 + j];
    float gg = Cs[sl][32 + jj] + bi[512 + j] + bh[512 + j];
    float go = Cs[sl][48 + jj] + bi[768 + j] + bh[768 + j];
    float si = 1.f / (1.f + expf(-gi));
    float sf = 1.f / (1.f + expf(-gf));
    float tg = tanhf(gg);
    float so = 1.f / (1.f + expf(-go));
    float cp = cprev[(size_t)s * H_ + j];
    float cn = sf * cp + si * tg;
    float hn = so * tanhf(cn);
    cbuf[(size_t)s * H_ + j] = cn;
    hout[(size_t)s * H_ + j] = hn;
  }
}

// ---------------- K3: feats = [hs_f|hs_b] @ w_out.T + b_out ----------------
__global__ __launch_bounds__(256) void k_out_gemm(
    const float* __restrict__ hs_f, const float* __restrict__ hs_b,
    const float* __restrict__ w_out, const float* __restrict__ b_out,
    float* __restrict__ feats) {
  __shared__ __align__(16) float wl[T_ * 512];
  for (int i = threadIdx.x; i < T_ * 512; i += 256) wl[i] = w_out[i];
  __syncthreads();
  int wave = threadIdx.x >> 6, lane = threadIdx.x & 63;
  size_t row = (size_t)blockIdx.x * 4 + wave;   // 0..16383
  float4 hf = *(const float4*)(hs_f + row * H_ + lane * 4);
  float4 hb = *(const float4*)(hs_b + row * H_ + lane * 4);
#pragma unroll
  for (int tag = 0; tag < T_; ++tag) {
    float4 wf = *(const float4*)&wl[tag * 512 + lane * 4];
    float4 wb = *(const float4*)&wl[tag * 512 + 256 + lane * 4];
    float p = hf.x * wf.x + hf.y * wf.y + hf.z * wf.z + hf.w * wf.w +
              hb.x * wb.x + hb.y * wb.y + hb.z * wb.z + hb.w * wb.w;
#pragma unroll
    for (int off = 32; off; off >>= 1) p += __shfl_xor(p, off, 64);
    if (lane == 0) feats[row * T_ + tag] = p + b_out[tag];
  }
}

// ---------------- K4: Viterbi fwd + backtrack, one wave per batch elem ----------------
__global__ __launch_bounds__(64) void k_viterbi(const float* __restrict__ feats,
                                                const float* __restrict__ trans,
                                                float* __restrict__ out) {
  __shared__ float fl[512 * T_];
  __shared__ unsigned char psi[511 * T_];
  const int b = blockIdx.x, tid = threadIdx.x;
  const float* fb = feats + (size_t)b * 512 * T_;
  for (int i = tid; i < 512 * T_; i += 64) fl[i] = fb[i];
  const int to = (tid < T_) ? tid : 0;
  float tr[T_];
#pragma unroll
  for (int f = 0; f < T_; ++f) tr[f] = trans[to * T_ + f];
  float delta = (tid == 9) ? 0.f : -10000.f;   // START=9
  __syncthreads();

  for (int s = 1; s < 512; ++s) {
    float m = -3.4e38f;
    int am = 0;
#pragma unroll
    for (int f = 0; f < T_; ++f) {
      float v = tr[f] + __shfl(delta, f, 64);
      if (v > m) { m = v; am = f; }          // strict >: first-max (jnp.argmax)
    }
    float nd = m + fl[s * T_ + to];
    if (tid < T_) psi[(s - 1) * T_ + tid] = (unsigned char)am;
    delta = nd;
  }
  float m = -3.4e38f;
  int last = 0;
#pragma unroll
  for (int j = 0; j < T_; ++j) {
    float v = __shfl(delta, j, 64);
    if (v > m) { m = v; last = j; }
  }
  __syncthreads();
  if (tid == 0) {
    out[b] = m;
    float* path = out + 32 + (size_t)b * 512;
    path[511] = (float)last;
    int nxt = last;
    for (int k = 510; k >= 0; --k) {
      nxt = psi[k * T_ + nxt];
      path[k] = (float)nxt;
    }
  }
}

}  // namespace

extern "C" void kernel_launch(void* const* d_in, const int* in_sizes, int n_in,
                              void* d_out, int out_size, void* d_ws, size_t ws_size,
                              hipStream_t stream) {
  const int* sent     = (const int*)d_in[0];
  const float* embed  = (const float*)d_in[1];
  const float* w_ih_f = (const float*)d_in[2];
  const float* w_hh_f = (const float*)d_in[3];
  const float* b_ih_f = (const float*)d_in[4];
  const float* b_hh_f = (const float*)d_in[5];
  const float* w_ih_b = (const float*)d_in[6];
  const float* w_hh_b = (const float*)d_in[7];
  const float* b_ih_b = (const float*)d_in[8];
  const float* b_hh_b = (const float*)d_in[9];
  const float* h0     = (const float*)d_in[10];
  const float* c0     = (const float*)d_in[11];
  const float* w_out  = (const float*)d_in[12];
  const float* b_out  = (const float*)d_in[13];
  const float* trans  = (const float*)d_in[14];

  float* ws    = (float*)d_ws;
  float* x     = ws;                 // 16384*256 = 4,194,304
  float* hs_f  = x + 4194304;        // 32*512*256 = 4,194,304
  float* hs_b  = hs_f + 4194304;     // 4,194,304
  float* c_f   = hs_b + 4194304;     // 131,072
  float* c_b   = c_f + 131072;       // 131,072
  float* feats = c_b + 131072;       // 180,224
  // total ~12.9M floats = ~52 MiB of ws

  k_gather<<<4096, 256, 0, stream>>>(sent, embed, x);
  for (int t = 0; t < 32; ++t)
    k_step<<<512, 256, 0, stream>>>(
        x, w_ih_f, w_hh_f, b_ih_f, b_hh_f, w_ih_b, w_hh_b, b_ih_b, b_hh_b,
        h0, c0, hs_f, hs_b, c_f, c_b, t);
  k_out_gemm<<<4096, 256, 0, stream>>>(hs_f, hs_b, w_out, b_out, feats);
  k_viterbi<<<32, 64, 0, stream>>>(feats, trans, (float*)d_out);
}